// Round 4
// baseline (790.159 us; speedup 1.0000x reference)
//
#include <hip/hip_runtime.h>
#include <math.h>

// Problem constants (16 x 1 x 1024 x 1024 fp32 pred/mask -> scalar fp32 loss)
#define BATCH 16
#define H 1024
#define W 1024
#define TILE 32
// Halo: 32x32 output tile + 16 halo on each side = 64x64 halo grid.
// Pixel (y,x) of tile <-> halo (y+16, x+16). Window p<=15: r2=rc+p<=62, r1=rc-p-1>=0.
// SAT = inclusive 2D prefix over the 64x64 halo; box = S[r2][c2]-S[r1][c2]-S[r2][c1]+S[r1][c1].
#define HDIM 64
#define SCOLS 65   // stride 65 % 32 == 1 -> scans and lookups stay 2-way/bank max (free, m136)
#define SEG  16    // scan segment length: 4 threads per 64-line

// Shape rationale (R3 post-mortem): the TILE=64/512-thread monolith ran at
// ~2 resident blocks/CU (Occ 47%) with every pipe <35% busy -- barrier-lockstep
// convoys with nothing else to schedule. TILE=32/256-thread blocks need only
// 16.7 KB LDS -> 8 blocks/CU (thread-cap), 4x the independent convoys, and
// each phase is 4-6x shorter. Redundant halo scan work rises but scans are a
// minor fraction of pipe time.

// d_ws accumulator layout: acc[b*5 + {0:weit,1:weit*bce,2:inter,3:union,4:mae}]
#define ACC_N (BATCH * 5)

__global__ __launch_bounds__(256, 8)
void adaptive_loss_main(const float* __restrict__ pred,
                        const float* __restrict__ mask,
                        float* __restrict__ acc) {
    __shared__ float sat[HDIM * SCOLS];
    __shared__ float red[4][5];

    const int tid = threadIdx.x;
    const int b   = blockIdx.z;
    const int ty0 = blockIdx.y * TILE;
    const int tx0 = blockIdx.x * TILE;
    const float* mimg = mask + (size_t)b * H * W;
    const float* pimg = pred + (size_t)b * H * W;

    // ---- Fused phase 0+1: all 256 threads. 4 threads per halo row, 16 floats
    //      each (4x float4 from global), prefix in registers, shfl-combine the
    //      4 segment totals (adjacent lanes), write row-scanned values to LDS. ----
    {
        const int row = tid >> 2, seg = tid & 3;
        const int gy  = ty0 - 16 + row;
        const int gx0 = tx0 - 16 + seg * SEG;
        const bool rowok = (gy >= 0) && (gy < H);
        const float* rp = mimg + (size_t)gy * W;

        float v[SEG];
        #pragma unroll
        for (int j = 0; j < 4; ++j) {
            int gx = gx0 + 4 * j;                  // 16B-aligned; chunk fully in or fully out
            float4 t;
            if (rowok && gx >= 0 && gx < W) t = *(const float4*)(rp + gx);
            else                            t = make_float4(0.f, 0.f, 0.f, 0.f);
            v[4 * j + 0] = t.x; v[4 * j + 1] = t.y;
            v[4 * j + 2] = t.z; v[4 * j + 3] = t.w;
        }
        #pragma unroll
        for (int i = 1; i < SEG; ++i) v[i] += v[i - 1];
        float tot = v[SEG - 1];
        float inc = tot;
        float t1 = __shfl_up(inc, 1); if (seg >= 1) inc += t1;
        float t2 = __shfl_up(inc, 2); if (seg >= 2) inc += t2;
        const float off = inc - tot;               // exclusive prefix of segment totals
        const int base = row * SCOLS + seg * SEG;  // banks 2-way max across the wave
        #pragma unroll
        for (int i = 0; i < SEG; ++i) sat[base + i] = v[i] + off;
    }
    __syncthreads();

    // ---- Prefetch phase-3 operands (one float4 of mask + pred per thread)
    //      into the col-scan latency window. ----
    float4 m4, p4;
    {
        const int y  = tid >> 3;          // 0..31
        const int x4 = (tid & 7) << 2;    // 0,4,...,28
        size_t off = (size_t)(ty0 + y) * W + (tx0 + x4);
        m4 = *(const float4*)(mimg + off);
        p4 = *(const float4*)(pimg + off);
    }

    // ---- Phase 2: col prefix. 4 threads per column, 16 independent reads,
    //      register chain, in-wave shfl segment combine, write back. ----
    {
        const int col = tid >> 2, seg = tid & 3;
        const int base = (seg * SEG) * SCOLS + col;
        float v[SEG];
        #pragma unroll
        for (int i = 0; i < SEG; ++i) v[i] = sat[base + i * SCOLS];
        #pragma unroll
        for (int i = 1; i < SEG; ++i) v[i] += v[i - 1];
        float tot = v[SEG - 1];
        float inc = tot;
        float t1 = __shfl_up(inc, 1); if (seg >= 1) inc += t1;
        float t2 = __shfl_up(inc, 2); if (seg >= 2) inc += t2;
        const float off = inc - tot;
        #pragma unroll
        for (int i = 0; i < SEG; ++i) sat[base + i * SCOLS] = v[i] + off;
    }
    __syncthreads();

    // ---- Phase 3: per-pixel fused compute from the SAT (4 px per thread) ----
    float s_w = 0.0f, s_wb = 0.0f, s_in = 0.0f, s_un = 0.0f, s_mae = 0.0f;

    const int pp[3]    = {1, 7, 15};
    const float inv[3] = {1.0f / 9.0f, 1.0f / 225.0f, 1.0f / 961.0f};

    {
        const int rc = (tid >> 3) + 16;          // halo row of this thread's pixels
        const int x4 = (tid & 7) << 2;

        #pragma unroll
        for (int q = 0; q < 4; ++q) {
            float m  = (&m4.x)[q];
            float pr = (&p4.x)[q];
            const int cc = x4 + q + 16;

            float w = 0.0f;
            #pragma unroll
            for (int j = 0; j < 3; ++j) {
                const int p  = pp[j];
                const int r2 = (rc + p) * SCOLS, r1 = (rc - p - 1) * SCOLS;
                const int c2 = cc + p,           c1 = cc - p - 1;
                float s = sat[r2 + c2] - sat[r1 + c2]
                        - sat[r2 + c1] + sat[r1 + c1];
                w += fabsf(s * inv[j] - m);
            }
            float weit = 1.0f + 5.0f * w;
            float t    = __expf(-fabsf(pr));                 // shared by bce & sigmoid
            float bce  = fmaxf(pr, 0.0f) - pr * m + __logf(1.0f + t);
            float u    = __builtin_amdgcn_rcpf(1.0f + t);    // 1/(1+e^-|pr|)
            float sig  = (pr >= 0.0f) ? u : 1.0f - u;

            s_w   += weit;
            s_wb  += weit * bce;
            s_in  += sig * m * weit;
            s_un  += (sig + m) * weit;
            s_mae += fabsf(sig - m);
        }
    }

    // ---- Phase 4: block reduction (wave shuffle, then LDS across 4 waves) ----
    #pragma unroll
    for (int off = 32; off > 0; off >>= 1) {
        s_w   += __shfl_down(s_w,   off);
        s_wb  += __shfl_down(s_wb,  off);
        s_in  += __shfl_down(s_in,  off);
        s_un  += __shfl_down(s_un,  off);
        s_mae += __shfl_down(s_mae, off);
    }
    int wave = tid >> 6, lane = tid & 63;
    if (lane == 0) {
        red[wave][0] = s_w;  red[wave][1] = s_wb; red[wave][2] = s_in;
        red[wave][3] = s_un; red[wave][4] = s_mae;
    }
    __syncthreads();
    if (tid == 0) {
        float r0 = 0, r1 = 0, r2 = 0, r3 = 0, r4 = 0;
        #pragma unroll
        for (int wv = 0; wv < 4; ++wv) {
            r0 += red[wv][0]; r1 += red[wv][1]; r2 += red[wv][2];
            r3 += red[wv][3]; r4 += red[wv][4];
        }
        atomicAdd(&acc[b * 5 + 0], r0);
        atomicAdd(&acc[b * 5 + 1], r1);
        atomicAdd(&acc[b * 5 + 2], r2);
        atomicAdd(&acc[b * 5 + 3], r3);
        atomicAdd(&acc[b * 5 + 4], r4);
    }
}

// Parallelized finalize: load the 80 accumulators cooperatively (one memory
// latency), then one thread does the cheap 16-batch scalar math from LDS.
__global__ void adaptive_loss_finalize(const float* __restrict__ acc,
                                       float* __restrict__ out) {
    __shared__ float a[ACC_N];
    int t = threadIdx.x;
    if (t < ACC_N) a[t] = acc[t];
    __syncthreads();
    if (t == 0) {
        float smae = 0.0f;
        for (int b = 0; b < BATCH; ++b) smae += a[b * 5 + 4];
        float mae = smae / (float)((size_t)BATCH * H * W);
        float tot = 0.0f;
        for (int b = 0; b < BATCH; ++b) {
            float Sw  = a[b * 5 + 0];
            float Swb = a[b * 5 + 1];
            float Si  = a[b * 5 + 2];
            float Su  = a[b * 5 + 3];
            float wbce = Swb / Sw;
            float wiou = 1.0f - (Si + 1.0f) / (Su - Si + 1.0f);
            float wmae = mae * Sw / (Sw - (float)(H * W));
            tot += 0.7f * (wbce + wiou + wmae);
        }
        out[0] = tot / (float)BATCH;
    }
}

extern "C" void kernel_launch(void* const* d_in, const int* in_sizes, int n_in,
                              void* d_out, int out_size, void* d_ws, size_t ws_size,
                              hipStream_t stream) {
    const float* pred = (const float*)d_in[0];
    const float* mask = (const float*)d_in[1];
    float* acc = (float*)d_ws;

    hipMemsetAsync(acc, 0, ACC_N * sizeof(float), stream);

    dim3 grid(W / TILE, H / TILE, BATCH);
    adaptive_loss_main<<<grid, 256, 0, stream>>>(pred, mask, acc);
    adaptive_loss_finalize<<<1, 128, 0, stream>>>(acc, (float*)d_out);
}

// Round 5
// 164.360 us; speedup vs baseline: 4.8075x; 4.8075x over previous
//
#include <hip/hip_runtime.h>
#include <math.h>

// Problem constants (16 x 1 x 1024 x 1024 fp32 pred/mask -> scalar fp32 loss)
#define BATCH 16
#define H 1024
#define W 1024
#define TILE 64
#define TILES_X (W / TILE)            // 16
#define TILES_Y (H / TILE)            // 16
#define NTILES  (TILES_X * TILES_Y)   // 256 blocks per batch image
// Halo layout: halo row hr in [0,96) <-> gy = ty0 - 16 + hr; same for cols.
// SAT = inclusive 2D prefix over the 96x96 halo; box = S[r2][c2]-S[r1][c2]-S[r2][c1]+S[r1][c1].
#define HDIM 96
#define SCOLS 97   // stride 97 % 32 == 1 -> scans and lookups land 2-way/bank max (free)
#define SEG  24    // scan segment length: 4 threads per 96-line

// d_ws layout: part[(c*BATCH + b)*NTILES + tile], c in [0,5) -- 5*16*256 floats (80 KB).
// NO atomics: R4 analysis showed every prior variant was pinned at ~115 same-line
// atomics/us GPU-wide (22.9 WG/us @TILE=64 vs 23.4 WG/us @TILE=32 -- invariant),
// i.e. the 5 atomicAdds/block to one 320B region serialized the whole kernel.
// Per-block partials now go to unique addresses; finalize reduces them.

__global__ __launch_bounds__(512, 6)
void adaptive_loss_main(const float* __restrict__ pred,
                        const float* __restrict__ mask,
                        float* __restrict__ part) {
    __shared__ float sat[HDIM * SCOLS];
    __shared__ float red[8][5];

    const int tid = threadIdx.x;
    const int b   = blockIdx.z;
    const int ty0 = blockIdx.y * TILE;
    const int tx0 = blockIdx.x * TILE;
    const float* mimg = mask + (size_t)b * H * W;
    const float* pimg = pred + (size_t)b * H * W;

    // ---- Fused phase 0+1: load row segment straight from global (6x float4),
    //      prefix in registers, shfl-combine the 4 segment totals (adjacent lanes),
    //      write the row-scanned values to LDS once. ----
    if (tid < 4 * HDIM) {
        const int row = tid >> 2, seg = tid & 3;
        const int gy  = ty0 - 16 + row;
        const int gx0 = tx0 - 16 + seg * SEG;
        const bool rowok = (gy >= 0) && (gy < H);
        const float* rp = mimg + (size_t)gy * W;

        float v[SEG];
        #pragma unroll
        for (int j = 0; j < 6; ++j) {
            int gx = gx0 + 4 * j;                  // 16B-aligned; chunk fully in or fully out
            float4 t;
            if (rowok && gx >= 0 && gx < W) t = *(const float4*)(rp + gx);
            else                            t = make_float4(0.f, 0.f, 0.f, 0.f);
            v[4 * j + 0] = t.x; v[4 * j + 1] = t.y;
            v[4 * j + 2] = t.z; v[4 * j + 3] = t.w;
        }
        #pragma unroll
        for (int i = 1; i < SEG; ++i) v[i] += v[i - 1];
        float tot = v[SEG - 1];
        float inc = tot;
        float t1 = __shfl_up(inc, 1); if (seg >= 1) inc += t1;
        float t2 = __shfl_up(inc, 2); if (seg >= 2) inc += t2;
        const float off = inc - tot;               // exclusive prefix of segment totals
        const int base = row * SCOLS + seg * SEG;
        #pragma unroll
        for (int i = 0; i < SEG; ++i) sat[base + i] = v[i] + off;
    }
    __syncthreads();

    // ---- Prefetch phase-3 operands into the col-scan latency window. ----
    float4 m4[2], p4[2];
    #pragma unroll
    for (int i = 0; i < 2; ++i) {
        int y  = (tid >> 4) + 32 * i;
        int x4 = (tid & 15) << 2;
        size_t off = (size_t)(ty0 + y) * W + (tx0 + x4);
        m4[i] = *(const float4*)(mimg + off);
        p4[i] = *(const float4*)(pimg + off);
    }

    // ---- Phase 2: col prefix. 4 threads per column, 24 independent reads,
    //      register chain, in-wave shfl segment combine, write back. ----
    if (tid < 4 * HDIM) {
        const int col = tid >> 2, seg = tid & 3;
        const int base = (seg * SEG) * SCOLS + col;
        float v[SEG];
        #pragma unroll
        for (int i = 0; i < SEG; ++i) v[i] = sat[base + i * SCOLS];
        #pragma unroll
        for (int i = 1; i < SEG; ++i) v[i] += v[i - 1];
        float tot = v[SEG - 1];
        float inc = tot;
        float t1 = __shfl_up(inc, 1); if (seg >= 1) inc += t1;
        float t2 = __shfl_up(inc, 2); if (seg >= 2) inc += t2;
        const float off = inc - tot;
        #pragma unroll
        for (int i = 0; i < SEG; ++i) sat[base + i * SCOLS] = v[i] + off;
    }
    __syncthreads();

    // ---- Phase 3: per-pixel fused compute from the SAT ----
    float s_w = 0.0f, s_wb = 0.0f, s_in = 0.0f, s_un = 0.0f, s_mae = 0.0f;

    const int pp[3]    = {1, 7, 15};
    const float inv[3] = {1.0f / 9.0f, 1.0f / 225.0f, 1.0f / 961.0f};

    #pragma unroll
    for (int i = 0; i < 2; ++i) {
        int y  = (tid >> 4) + 32 * i;   // 0..63
        int x4 = (tid & 15) << 2;       // 0,4,...,60
        const int rc = y + 16;

        #pragma unroll
        for (int q = 0; q < 4; ++q) {
            float m  = (&m4[i].x)[q];
            float pr = (&p4[i].x)[q];
            int cc = x4 + q + 16;

            float w = 0.0f;
            #pragma unroll
            for (int j = 0; j < 3; ++j) {
                int r2 = (rc + pp[j]) * SCOLS, r1 = (rc - pp[j] - 1) * SCOLS;
                int c2 = cc + pp[j],           c1 = cc - pp[j] - 1;
                float s = sat[r2 + c2] - sat[r1 + c2]
                        - sat[r2 + c1] + sat[r1 + c1];
                w += fabsf(s * inv[j] - m);
            }
            float weit = 1.0f + 5.0f * w;
            float t    = __expf(-fabsf(pr));                 // shared by bce & sigmoid
            float bce  = fmaxf(pr, 0.0f) - pr * m + __logf(1.0f + t);
            float u    = __builtin_amdgcn_rcpf(1.0f + t);    // 1/(1+e^-|pr|)
            float sig  = (pr >= 0.0f) ? u : 1.0f - u;

            s_w   += weit;
            s_wb  += weit * bce;
            s_in  += sig * m * weit;
            s_un  += (sig + m) * weit;
            s_mae += fabsf(sig - m);
        }
    }

    // ---- Phase 4: block reduction, then 5 plain stores to unique addresses ----
    #pragma unroll
    for (int off = 32; off > 0; off >>= 1) {
        s_w   += __shfl_down(s_w,   off);
        s_wb  += __shfl_down(s_wb,  off);
        s_in  += __shfl_down(s_in,  off);
        s_un  += __shfl_down(s_un,  off);
        s_mae += __shfl_down(s_mae, off);
    }
    int wave = tid >> 6, lane = tid & 63;
    if (lane == 0) {
        red[wave][0] = s_w;  red[wave][1] = s_wb; red[wave][2] = s_in;
        red[wave][3] = s_un; red[wave][4] = s_mae;
    }
    __syncthreads();
    if (tid < 5) {
        float r = 0.0f;
        #pragma unroll
        for (int wv = 0; wv < 8; ++wv) r += red[wv][tid];
        const int tile = blockIdx.y * TILES_X + blockIdx.x;
        part[((size_t)tid * BATCH + b) * NTILES + tile] = r;
    }
}

// Finalize: one block, 1024 threads. Wave w reduces batch w (NTILES=256 tiles,
// 4 per lane, fully coalesced comp-major loads), shuffle-reduce, then thread 0
// does the cheap scalar epilogue. Replaces atomic accumulation + serial finalize.
__global__ __launch_bounds__(1024)
void adaptive_loss_finalize(const float* __restrict__ part,
                            float* __restrict__ out) {
    __shared__ float sums[BATCH][5];
    const int wv   = threadIdx.x >> 6;   // 0..15 == batch
    const int lane = threadIdx.x & 63;

    float v[5];
    #pragma unroll
    for (int c = 0; c < 5; ++c) {
        float s = 0.0f;
        #pragma unroll
        for (int r = 0; r < NTILES / 64; ++r)
            s += part[((size_t)c * BATCH + wv) * NTILES + r * 64 + lane];
        v[c] = s;
    }
    #pragma unroll
    for (int off = 32; off > 0; off >>= 1) {
        #pragma unroll
        for (int c = 0; c < 5; ++c) v[c] += __shfl_down(v[c], off);
    }
    if (lane == 0) {
        #pragma unroll
        for (int c = 0; c < 5; ++c) sums[wv][c] = v[c];
    }
    __syncthreads();

    if (threadIdx.x == 0) {
        float smae = 0.0f;
        for (int b = 0; b < BATCH; ++b) smae += sums[b][4];
        float mae = smae / (float)((size_t)BATCH * H * W);
        float tot = 0.0f;
        for (int b = 0; b < BATCH; ++b) {
            float Sw  = sums[b][0];
            float Swb = sums[b][1];
            float Si  = sums[b][2];
            float Su  = sums[b][3];
            float wbce = Swb / Sw;
            float wiou = 1.0f - (Si + 1.0f) / (Su - Si + 1.0f);
            float wmae = mae * Sw / (Sw - (float)(H * W));
            tot += 0.7f * (wbce + wiou + wmae);
        }
        out[0] = tot / (float)BATCH;
    }
}

extern "C" void kernel_launch(void* const* d_in, const int* in_sizes, int n_in,
                              void* d_out, int out_size, void* d_ws, size_t ws_size,
                              hipStream_t stream) {
    const float* pred = (const float*)d_in[0];
    const float* mask = (const float*)d_in[1];
    float* part = (float*)d_ws;   // 5 * BATCH * NTILES floats = 80 KB, fully overwritten

    dim3 grid(TILES_X, TILES_Y, BATCH);
    adaptive_loss_main<<<grid, 512, 0, stream>>>(pred, mask, part);
    adaptive_loss_finalize<<<1, 1024, 0, stream>>>(part, (float*)d_out);
}